// Round 1
// baseline (865.248 us; speedup 1.0000x reference)
//
#include <hip/hip_runtime.h>
#include <stdint.h>

typedef unsigned short u16;
typedef __attribute__((ext_vector_type(8))) short short8;
typedef __attribute__((ext_vector_type(8))) __bf16 bf16x8;
typedef __attribute__((ext_vector_type(4))) float f32x4;
typedef __attribute__((ext_vector_type(4))) u16 u16x4;

// Problem constants: B2=16, N=1024, C=128, H=8, CH=1024, B=8, D=B*CH=8192
#define CDINV (1.0f / 8388608.0f)

__device__ __forceinline__ u16 f2b(float f) {
  union { float f; unsigned u; } v; v.f = f;
  unsigned r = (v.u + 0x7FFFu + ((v.u >> 16) & 1u)) >> 16;
  return (u16)r;
}
__device__ __forceinline__ float b2f(u16 h) {
  union { unsigned u; float f; } v; v.u = ((unsigned)h) << 16;
  return v.f;
}

__device__ __forceinline__ void gll16(const void* g, void* l) {
  __builtin_amdgcn_global_load_lds((const __attribute__((address_space(1))) void*)g,
                                   (__attribute__((address_space(3))) void*)l, 16, 0, 0);
}

// m97-style 128x128 tile BT-GEMM core: A [row][K] (lda), B [col][K] (ldb),
// BK=32, 4 waves, out acc[4][4] f32x4 in the 16x16x32 C/D layout.
// chunkA: A's K axis is chunked [k>>10][..][k&1023] with chunk stride 1048576 (PV's v_flat).
__device__ __forceinline__ void gemm_core(const u16* __restrict__ Ab, int lda,
                                          const u16* __restrict__ Bb, int ldb,
                                          int ksteps, int chunkA,
                                          u16 (&ldsA)[4096], u16 (&ldsB)[4096],
                                          f32x4 acc[4][4]) {
  const int t = threadIdx.x;
  const int w = t >> 6, l = t & 63;
  const int wr = (w >> 1) << 6, wc = (w & 1) << 6;
  const int srow = (w << 4) + (l >> 2);   // staging row within a 64-row block
  const int skk = (l & 3) << 3;           // staging k offset (elements)
  const int fr = l & 15;
  const int fk = (l >> 4) << 3;
  for (int ks = 0; ks < ksteps; ++ks) {
    const int k0 = ks << 5;
    size_t aoff = chunkA ? ((size_t)(k0 >> 10) * 1048576u + (size_t)(k0 & 1023))
                         : (size_t)k0;
    __syncthreads();  // previous tile's LDS reads done before overwrite
#pragma unroll
    for (int i = 0; i < 2; ++i) {
      gll16(Ab + (size_t)(i * 64 + srow) * (size_t)lda + aoff + skk,
            ldsA + i * 2048 + w * 512);
      gll16(Bb + (size_t)(i * 64 + srow) * (size_t)ldb + (size_t)k0 + skk,
            ldsB + i * 2048 + w * 512);
    }
    __syncthreads();  // compiler drains vmcnt(0) before s_barrier -> LDS ready
    bf16x8 af[4], bfv[4];
#pragma unroll
    for (int m = 0; m < 4; ++m)
      af[m] = __builtin_bit_cast(bf16x8,
              *(const short8*)(ldsA + (wr + m * 16 + fr) * 32 + fk));
#pragma unroll
    for (int n = 0; n < 4; ++n)
      bfv[n] = __builtin_bit_cast(bf16x8,
              *(const short8*)(ldsB + (wc + n * 16 + fr) * 32 + fk));
#pragma unroll
    for (int m = 0; m < 4; ++m)
#pragma unroll
      for (int n = 0; n < 4; ++n)
        acc[m][n] = __builtin_amdgcn_mfma_f32_16x16x32_bf16(af[m], bfv[n],
                                                            acc[m][n], 0, 0, 0);
  }
}

// ---- kernel 1: f32 -> bf16 conversion of emb + all weights; zero stats ----
__global__ __launch_bounds__(256) void k_convert(
    const float* __restrict__ emb, const float* __restrict__ wq,
    const float* __restrict__ wk, const float* __restrict__ wv,
    const float* __restrict__ wo, u16* __restrict__ embB, u16* __restrict__ wqB,
    u16* __restrict__ wkB, u16* __restrict__ wvB, u16* __restrict__ woB,
    float* __restrict__ S) {
  int i = blockIdx.x * 256 + threadIdx.x;
  if (i < 16) S[i] = 0.0f;
  if (i < 2097152) { embB[i] = f2b(emb[i]); return; }
  int j = i - 2097152;
  if (j < 131072) { wqB[j] = f2b(wq[j]); return; }
  j -= 131072;
  if (j < 131072) { wkB[j] = f2b(wk[j]); return; }
  j -= 131072;
  if (j < 131072) { wvB[j] = f2b(wv[j]); return; }
  j -= 131072;
  if (j < 131072) { woB[j] = f2b(wo[j]); return; }
}

// ---- kernel 2: projections. q->qT[b][ch][n], k->kT[b][ch][n], v natural [b][n][ch]
__global__ __launch_bounds__(256) void k_proj(
    const u16* __restrict__ embB, const u16* __restrict__ wqB,
    const u16* __restrict__ wkB, const u16* __restrict__ wvB,
    u16* __restrict__ qT, u16* __restrict__ kT, u16* __restrict__ vb) {
  __shared__ u16 ldsA[4096], ldsB[4096];
  const int x = blockIdx.x, b = blockIdx.y, mat = blockIdx.z;
  const int n0 = (x & 7) << 7, ch0 = (x >> 3) << 7;
  const int rowbase = ((mat == 0 ? b : b + 8) << 10) + n0;
  const u16* W = (mat == 0) ? wqB : ((mat == 1) ? wkB : wvB);
  f32x4 acc[4][4];
#pragma unroll
  for (int m = 0; m < 4; ++m)
#pragma unroll
    for (int n = 0; n < 4; ++n) acc[m][n] = (f32x4){0.f, 0.f, 0.f, 0.f};
  gemm_core(embB + (size_t)rowbase * 128, 128, W + (size_t)ch0 * 128, 128, 4, 0,
            ldsA, ldsB, acc);
  const int t = threadIdx.x, w = t >> 6, l = t & 63;
  const int wr = (w >> 1) << 6, wc = (w & 1) << 6;
  if (mat < 2) {
    u16* dst = (mat == 0 ? qT : kT) + (size_t)b * 1048576u;
#pragma unroll
    for (int m = 0; m < 4; ++m)
#pragma unroll
      for (int n = 0; n < 4; ++n) {
        int rl = wr + m * 16 + ((l >> 4) << 2);  // local n (4 consecutive via j)
        int cl = wc + n * 16 + (l & 15);         // local ch
        u16x4 pk;
#pragma unroll
        for (int j = 0; j < 4; ++j) pk[j] = f2b(acc[m][n][j]);
        *(u16x4*)(dst + (size_t)(ch0 + cl) * 1024u + (size_t)(n0 + rl)) = pk;
      }
  } else {
    u16* dst = vb + (size_t)b * 1048576u;
#pragma unroll
    for (int m = 0; m < 4; ++m)
#pragma unroll
      for (int n = 0; n < 4; ++n) {
        int rl = wr + m * 16 + ((l >> 4) << 2);
        int cl = wc + n * 16 + (l & 15);
#pragma unroll
        for (int j = 0; j < 4; ++j)
          dst[(size_t)(n0 + rl + j) * 1024u + (size_t)(ch0 + cl)] = f2b(acc[m][n][j]);
      }
  }
}

// ---- kernel 3: scores[b][c][d] = sum_n qT[b][c][n]*kT[d][n]; bf16 out + batch sum/sumsq
__global__ __launch_bounds__(256) void k_qk(const u16* __restrict__ qT,
                                            const u16* __restrict__ kT,
                                            u16* __restrict__ sc,
                                            float* __restrict__ S) {
  __shared__ u16 ldsA[4096], ldsB[4096];
  const int dt = blockIdx.x, ct = blockIdx.y, b = blockIdx.z;
  const int c0 = ct << 7, d0 = dt << 7;
  f32x4 acc[4][4];
#pragma unroll
  for (int m = 0; m < 4; ++m)
#pragma unroll
    for (int n = 0; n < 4; ++n) acc[m][n] = (f32x4){0.f, 0.f, 0.f, 0.f};
  const u16* Ab = qT + (size_t)b * 1048576u + (size_t)c0 * 1024u;
  const u16* Bb = kT + (size_t)(dt >> 3) * 1048576u + (size_t)((dt & 7) << 7) * 1024u;
  gemm_core(Ab, 1024, Bb, 1024, 32, 0, ldsA, ldsB, acc);
  const int t = threadIdx.x, w = t >> 6, l = t & 63;
  const int wr = (w >> 1) << 6, wc = (w & 1) << 6;
  u16* dstb = sc + (size_t)b * 8388608u;
  float ls = 0.f, lq = 0.f;
#pragma unroll
  for (int m = 0; m < 4; ++m)
#pragma unroll
    for (int n = 0; n < 4; ++n) {
      int rl = wr + m * 16 + ((l >> 4) << 2);
      int cl = wc + n * 16 + (l & 15);
#pragma unroll
      for (int j = 0; j < 4; ++j) {
        float sv = acc[m][n][j];
        ls += sv; lq += sv * sv;
        dstb[(size_t)(c0 + rl + j) * 8192u + (size_t)(d0 + cl)] = f2b(sv);
      }
    }
#pragma unroll
  for (int off = 32; off; off >>= 1) {
    ls += __shfl_down(ls, off);
    lq += __shfl_down(lq, off);
  }
  if (l == 0) { atomicAdd(&S[b], ls); atomicAdd(&S[8 + b], lq); }
}

// ---- kernel 4: per-batch rsqrt(var+eps). mean shift cancels in softmax. ----
__global__ void k_stats(const float* __restrict__ S, float* __restrict__ r) {
  int t = threadIdx.x;
  if (t < 8) {
    float mean = S[t] * CDINV;
    float var = S[8 + t] * CDINV - mean * mean;
    r[t] = rsqrtf(var + 1e-5f);
  }
}

// ---- kernel 5: in-place row softmax of r*s over d=8192; one WG per (b,c) row
__global__ __launch_bounds__(256) void k_softmax(u16* __restrict__ sc,
                                                 const float* __restrict__ rb) {
  const int wg = blockIdx.x;
  const int b = wg >> 10, c = wg & 1023;
  u16* rowp = sc + (size_t)b * 8388608u + (size_t)c * 8192u;
  const float rl = rb[b] * 1.44269504089f;  // r * log2(e)
  const int t = threadIdx.x, w = t >> 6, l = t & 63;
  __shared__ float red[4];
  __shared__ float bcast;
  float v[4][8];
  float m = -1e30f;
#pragma unroll
  for (int i = 0; i < 4; ++i) {
    short8 x = *(const short8*)(rowp + i * 2048 + t * 8);
#pragma unroll
    for (int j = 0; j < 8; ++j) {
      v[i][j] = b2f((u16)x[j]);
      m = fmaxf(m, v[i][j]);
    }
  }
#pragma unroll
  for (int off = 32; off; off >>= 1) m = fmaxf(m, __shfl_xor(m, off));
  if (l == 0) red[w] = m;
  __syncthreads();
  if (t == 0) bcast = fmaxf(fmaxf(red[0], red[1]), fmaxf(red[2], red[3]));
  __syncthreads();
  m = bcast;
  float s = 0.f;
#pragma unroll
  for (int i = 0; i < 4; ++i)
#pragma unroll
    for (int j = 0; j < 8; ++j) {
      v[i][j] = exp2f((v[i][j] - m) * rl);
      s += v[i][j];
    }
#pragma unroll
  for (int off = 32; off; off >>= 1) s += __shfl_xor(s, off);
  __syncthreads();  // red[] reads from max phase are done (t0 read before bcast)
  if (l == 0) red[w] = s;
  __syncthreads();
  if (t == 0) bcast = 1.0f / (red[0] + red[1] + red[2] + red[3]);
  __syncthreads();
  const float inv = bcast;
#pragma unroll
  for (int i = 0; i < 4; ++i) {
    short8 x;
#pragma unroll
    for (int j = 0; j < 8; ++j) x[j] = (short)f2b(v[i][j] * inv);
    *(short8*)(rowp + i * 2048 + t * 8) = x;
  }
}

// ---- kernel 6: ctx[b][n][c] = sum_d v_flat[n][d]*attn[b][c][d] ----
__global__ __launch_bounds__(256) void k_pv(const u16* __restrict__ vb,
                                            const u16* __restrict__ sc,
                                            u16* __restrict__ ctx) {
  __shared__ u16 ldsA[4096], ldsB[4096];
  const int x = blockIdx.x, b = blockIdx.y;
  const int n0 = (x & 7) << 7, c0 = (x >> 3) << 7;
  f32x4 acc[4][4];
#pragma unroll
  for (int m = 0; m < 4; ++m)
#pragma unroll
    for (int n = 0; n < 4; ++n) acc[m][n] = (f32x4){0.f, 0.f, 0.f, 0.f};
  const u16* Ab = vb + (size_t)n0 * 1024u;  // chunked over k (b' chunks of 1024)
  const u16* Bb = sc + (size_t)b * 8388608u + (size_t)c0 * 8192u;
  gemm_core(Ab, 1024, Bb, 8192, 256, 1, ldsA, ldsB, acc);
  const int t = threadIdx.x, w = t >> 6, l = t & 63;
  const int wr = (w >> 1) << 6, wc = (w & 1) << 6;
  u16* dst = ctx + (size_t)b * 1048576u;
#pragma unroll
  for (int m = 0; m < 4; ++m)
#pragma unroll
    for (int n = 0; n < 4; ++n) {
      int rl = wr + m * 16 + ((l >> 4) << 2);
      int cl = wc + n * 16 + (l & 15);
#pragma unroll
      for (int j = 0; j < 4; ++j)
        dst[(size_t)(n0 + rl + j) * 1024u + (size_t)(c0 + cl)] = f2b(acc[m][n][j]);
    }
}

// ---- kernel 7: out[row][co] = sum_ch ctx[row][ch]*Wo[co][ch], f32 out ----
__global__ __launch_bounds__(256) void k_out(const u16* __restrict__ ctx,
                                             const u16* __restrict__ woB,
                                             float* __restrict__ out) {
  __shared__ u16 ldsA[4096], ldsB[4096];
  const int x = blockIdx.x;  // 64 row-tiles of 128
  f32x4 acc[4][4];
#pragma unroll
  for (int m = 0; m < 4; ++m)
#pragma unroll
    for (int n = 0; n < 4; ++n) acc[m][n] = (f32x4){0.f, 0.f, 0.f, 0.f};
  gemm_core(ctx + (size_t)x * 128u * 1024u, 1024, woB, 1024, 32, 0, ldsA, ldsB, acc);
  const int t = threadIdx.x, w = t >> 6, l = t & 63;
  const int wr = (w >> 1) << 6, wc = (w & 1) << 6;
#pragma unroll
  for (int m = 0; m < 4; ++m)
#pragma unroll
    for (int n = 0; n < 4; ++n) {
      int rl = wr + m * 16 + ((l >> 4) << 2);
      int cl = wc + n * 16 + (l & 15);
      if (cl < 128) {
#pragma unroll
        for (int j = 0; j < 4; ++j)
          out[(size_t)(x * 128 + rl + j) * 128u + (size_t)cl] = acc[m][n][j];
      }
    }
}

extern "C" void kernel_launch(void* const* d_in, const int* in_sizes, int n_in,
                              void* d_out, int out_size, void* d_ws, size_t ws_size,
                              hipStream_t stream) {
  const float* emb = (const float*)d_in[0];
  const float* wq = (const float*)d_in[1];
  const float* wk = (const float*)d_in[2];
  const float* wv = (const float*)d_in[3];
  const float* wo = (const float*)d_in[4];
  float* out = (float*)d_out;

  char* w = (char*)d_ws;
  // ws layout (total ~181 MB):
  u16* sc = (u16*)w;                        // scores/attn bf16: 8*1024*8192 = 134217728 B
  u16* qT = (u16*)(w + 134217728);          // 16 MB  (aliased as ctx after QK)
  u16* kT = qT + 8388608;                   // 16 MB
  u16* vb = kT + 8388608;                   // 16 MB
  u16* embB = vb + 8388608;                 // 4 MB
  u16* wqB = embB + 2097152;
  u16* wkB = wqB + 131072;
  u16* wvB = wkB + 131072;
  u16* woB = wvB + 131072;
  float* S = (float*)(woB + 131072);        // S[0..7]=sum, S[8..15]=sumsq
  float* r = S + 16;
  u16* ctx = qT;                            // alias: qT dead after k_qk

  k_convert<<<10240, 256, 0, stream>>>(emb, wq, wk, wv, wo, embB, wqB, wkB, wvB,
                                       woB, S);
  k_proj<<<dim3(64, 8, 3), 256, 0, stream>>>(embB, wqB, wkB, wvB, qT, kT, vb);
  k_qk<<<dim3(64, 8, 8), 256, 0, stream>>>(qT, kT, sc, S);
  k_stats<<<1, 64, 0, stream>>>(S, r);
  k_softmax<<<8192, 256, 0, stream>>>(sc, r);
  k_pv<<<dim3(64, 8), 256, 0, stream>>>(vb, sc, ctx);
  k_out<<<64, 256, 0, stream>>>(ctx, woB, out);
}

// Round 5
// 626.191 us; speedup vs baseline: 1.3818x; 1.3818x over previous
//
#include <hip/hip_runtime.h>
#include <stdint.h>

typedef unsigned short u16;
typedef __attribute__((ext_vector_type(8))) short short8;
typedef __attribute__((ext_vector_type(8))) __bf16 bf16x8;
typedef __attribute__((ext_vector_type(4))) float f32x4;
typedef __attribute__((ext_vector_type(4))) u16 u16x4;

// Problem constants: B2=16, N=1024, C=128, H=8, CH=1024, B=8, D=B*CH=8192
#define CDINV (1.0f / 8388608.0f)

__device__ __forceinline__ u16 f2b(float f) {
  union { float f; unsigned u; } v; v.f = f;
  unsigned r = (v.u + 0x7FFFu + ((v.u >> 16) & 1u)) >> 16;
  return (u16)r;
}
__device__ __forceinline__ float b2f(u16 h) {
  union { unsigned u; float f; } v; v.u = ((unsigned)h) << 16;
  return v.f;
}

// LDS dest is wave-uniform; hardware scatters lane i at dest + i*16.
__device__ __forceinline__ void gll16(const void* g, void* l) {
  __builtin_amdgcn_global_load_lds((const __attribute__((address_space(1))) void*)g,
                                   (__attribute__((address_space(3))) void*)l, 16, 0, 0);
}

// ---------------- m97-style core (small GEMMs: proj/out) -------------------
__device__ __forceinline__ void gemm_core(const u16* __restrict__ Ab, int lda,
                                          const u16* __restrict__ Bb, int ldb,
                                          int ksteps,
                                          u16 (&ldsA)[4096], u16 (&ldsB)[4096],
                                          f32x4 acc[4][4]) {
  const int t = threadIdx.x;
  const int w = t >> 6, l = t & 63;
  const int wr = (w >> 1) << 6, wc = (w & 1) << 6;
  const int srow = (w << 4) + (l >> 2);
  const int skk = (l & 3) << 3;
  const int fr = l & 15;
  const int fk = (l >> 4) << 3;
  for (int ks = 0; ks < ksteps; ++ks) {
    const int k0 = ks << 5;
    __syncthreads();
#pragma unroll
    for (int i = 0; i < 2; ++i) {
      gll16(Ab + (size_t)(i * 64 + srow) * (size_t)lda + (size_t)k0 + skk,
            ldsA + i * 2048 + w * 512);
      gll16(Bb + (size_t)(i * 64 + srow) * (size_t)ldb + (size_t)k0 + skk,
            ldsB + i * 2048 + w * 512);
    }
    __syncthreads();
    bf16x8 af[4], bfv[4];
#pragma unroll
    for (int m = 0; m < 4; ++m)
      af[m] = __builtin_bit_cast(bf16x8,
              *(const short8*)(ldsA + (wr + m * 16 + fr) * 32 + fk));
#pragma unroll
    for (int n = 0; n < 4; ++n)
      bfv[n] = __builtin_bit_cast(bf16x8,
              *(const short8*)(ldsB + (wc + n * 16 + fr) * 32 + fk));
#pragma unroll
    for (int m = 0; m < 4; ++m)
#pragma unroll
      for (int n = 0; n < 4; ++n)
        acc[m][n] = __builtin_amdgcn_mfma_f32_16x16x32_bf16(af[m], bfv[n],
                                                            acc[m][n], 0, 0, 0);
  }
}

// ---- kernel 1: f32 -> bf16 conversion of emb + all weights; zero stats ----
__global__ __launch_bounds__(256) void k_convert(
    const float* __restrict__ emb, const float* __restrict__ wq,
    const float* __restrict__ wk, const float* __restrict__ wv,
    const float* __restrict__ wo, u16* __restrict__ embB, u16* __restrict__ wqB,
    u16* __restrict__ wkB, u16* __restrict__ wvB, u16* __restrict__ woB,
    float* __restrict__ S) {
  int i = blockIdx.x * 256 + threadIdx.x;
  if (i < 16) S[i] = 0.0f;
  if (i < 2097152) { embB[i] = f2b(emb[i]); return; }
  int j = i - 2097152;
  if (j < 131072) { wqB[j] = f2b(wq[j]); return; }
  j -= 131072;
  if (j < 131072) { wkB[j] = f2b(wk[j]); return; }
  j -= 131072;
  if (j < 131072) { wvB[j] = f2b(wv[j]); return; }
  j -= 131072;
  if (j < 131072) { woB[j] = f2b(wo[j]); return; }
}

// ---- kernel 2: projections. q->qT[b][ch][n], k->kT[b][ch][n], v natural ----
__global__ __launch_bounds__(256) void k_proj(
    const u16* __restrict__ embB, const u16* __restrict__ wqB,
    const u16* __restrict__ wkB, const u16* __restrict__ wvB,
    u16* __restrict__ qT, u16* __restrict__ kT, u16* __restrict__ vb) {
  __shared__ u16 ldsA[4096], ldsB[4096];
  const int x = blockIdx.x, b = blockIdx.y, mat = blockIdx.z;
  const int n0 = (x & 7) << 7, ch0 = (x >> 3) << 7;
  const int rowbase = ((mat == 0 ? b : b + 8) << 10) + n0;
  const u16* W = (mat == 0) ? wqB : ((mat == 1) ? wkB : wvB);
  f32x4 acc[4][4];
#pragma unroll
  for (int m = 0; m < 4; ++m)
#pragma unroll
    for (int n = 0; n < 4; ++n) acc[m][n] = (f32x4){0.f, 0.f, 0.f, 0.f};
  gemm_core(embB + (size_t)rowbase * 128, 128, W + (size_t)ch0 * 128, 128, 4,
            ldsA, ldsB, acc);
  const int t = threadIdx.x, w = t >> 6, l = t & 63;
  const int wr = (w >> 1) << 6, wc = (w & 1) << 6;
  if (mat < 2) {
    u16* dst = (mat == 0 ? qT : kT) + (size_t)b * 1048576u;
#pragma unroll
    for (int m = 0; m < 4; ++m)
#pragma unroll
      for (int n = 0; n < 4; ++n) {
        int rl = wr + m * 16 + ((l >> 4) << 2);
        int cl = wc + n * 16 + (l & 15);
        u16x4 pk;
#pragma unroll
        for (int j = 0; j < 4; ++j) pk[j] = f2b(acc[m][n][j]);
        *(u16x4*)(dst + (size_t)(ch0 + cl) * 1024u + (size_t)(n0 + rl)) = pk;
      }
  } else {
    u16* dst = vb + (size_t)b * 1048576u;
#pragma unroll
    for (int m = 0; m < 4; ++m)
#pragma unroll
      for (int n = 0; n < 4; ++n) {
        int rl = wr + m * 16 + ((l >> 4) << 2);
        int cl = wc + n * 16 + (l & 15);
#pragma unroll
        for (int j = 0; j < 4; ++j)
          dst[(size_t)(n0 + rl + j) * 1024u + (size_t)(ch0 + cl)] = f2b(acc[m][n][j]);
      }
  }
}

// ---- kernel 3: QK = 8192x8192x1024 BT-GEMM, 256x256 tile, 2-phase dbuf ----
// A = qT row (b*1024+c) over n; B = kT row (b'*1024+ch') over n; lda=ldb=1024.
// 8 waves (2Mx4N); per-wave 128x64 out (acc[8][4]). BK=32.
// LDS 64KB: buf p at p*32KB; A [0,16K) byte=row*64, B [16K,32K). Linear (no swz).
// Verified "minimum 2-phase" schedule: STAGE(next) -> compute(cur) -> syncthreads.
__global__ __launch_bounds__(512, 2) void k_qk2(const u16* __restrict__ qT,
                                                const u16* __restrict__ kT,
                                                u16* __restrict__ sc,
                                                float* __restrict__ S) {
  __shared__ u16 lds[32768];  // 64 KiB
  char* ldsb = (char*)lds;
  const int bid = blockIdx.x;
  // XCD swizzle: xcd (bid&7) owns mt in {4x..4x+3} -> A panels L2-resident.
  const int mt = (bid & 7) * 4 + (bid >> 8);
  const int nt = (bid >> 3) & 31;
  const int t = threadIdx.x, w = t >> 6, l = t & 63;
  const int wm = w >> 2, wn = w & 3;
  const int fr = l & 15, fq = l >> 4;
  const int sr0 = w * 16 + (l >> 2);   // staged row; 4 lanes per row
  const int kk = (l & 3) << 3;         // k-chunk within sub-tile (elements)
  const int lbase = w * 1024;          // wave-uniform LDS byte base
  const u16* A0 = qT + (size_t)(mt * 256 + sr0) * 1024u + kk;
  const u16* B0 = kT + (size_t)(nt * 256 + sr0) * 1024u + kk;
  const int ard = (wm * 128 + fr) * 64 + fq * 16;
  const int brd = 16384 + (wn * 64 + fr) * 64 + fq * 16;

  f32x4 acc[8][4];
#pragma unroll
  for (int m = 0; m < 8; ++m)
#pragma unroll
    for (int n = 0; n < 4; ++n) acc[m][n] = (f32x4){0.f, 0.f, 0.f, 0.f};

#define QK_STAGE(s_, p_)                                                    \
  {                                                                         \
    const int k0_ = (s_) << 5;                                              \
    char* la_ = ldsb + (p_) * 32768 + lbase;                                \
    gll16(A0 + k0_, la_);                                                   \
    gll16(A0 + k0_ + 131072, la_ + 8192);                                   \
    char* lb_ = ldsb + (p_) * 32768 + 16384 + lbase;                        \
    gll16(B0 + k0_, lb_);                                                   \
    gll16(B0 + k0_ + 131072, lb_ + 8192);                                   \
  }

  QK_STAGE(0, 0);
  __syncthreads();
  for (int s = 0; s < 32; ++s) {
    const int p = s & 1;
    if (s < 31) QK_STAGE(s + 1, p ^ 1);  // issue next tile before compute
    char* base = ldsb + p * 32768;
    bf16x8 af[8], bfv[4];
#pragma unroll
    for (int m = 0; m < 8; ++m)
      af[m] = __builtin_bit_cast(bf16x8, *(const short8*)(base + ard + m * 1024));
#pragma unroll
    for (int n = 0; n < 4; ++n)
      bfv[n] = __builtin_bit_cast(bf16x8, *(const short8*)(base + brd + n * 1024));
#pragma unroll
    for (int m = 0; m < 8; ++m)
#pragma unroll
      for (int n = 0; n < 4; ++n)
        acc[m][n] = __builtin_amdgcn_mfma_f32_16x16x32_bf16(af[m], bfv[n],
                                                            acc[m][n], 0, 0, 0);
    __syncthreads();  // drains vmcnt(0): next buffer complete; WAR protected
  }
#undef QK_STAGE

  // epilogue: bf16 stores + per-batch sum/sumsq atomics
  const int mrow0 = mt * 256 + wm * 128 + fq * 4;
  const int ncol0 = nt * 256 + wn * 64 + fr;
  const int b = mt >> 2;  // uniform per block
  float ls = 0.f, lq = 0.f;
#pragma unroll
  for (int m = 0; m < 8; ++m)
#pragma unroll
    for (int n = 0; n < 4; ++n) {
      const int row = mrow0 + m * 16;
      const int col = ncol0 + n * 16;
#pragma unroll
      for (int j = 0; j < 4; ++j) {
        float sv = acc[m][n][j];
        ls += sv; lq += sv * sv;
        sc[(size_t)(row + j) * 8192u + (size_t)col] = f2b(sv);
      }
    }
#pragma unroll
  for (int off = 32; off; off >>= 1) {
    ls += __shfl_down(ls, off);
    lq += __shfl_down(lq, off);
  }
  if (l == 0) { atomicAdd(&S[b], ls); atomicAdd(&S[8 + b], lq); }
}

// ---- kernel 4: per-batch rsqrt(var+eps). mean shift cancels in softmax. ----
__global__ void k_stats(const float* __restrict__ S, float* __restrict__ r) {
  int t = threadIdx.x;
  if (t < 8) {
    float mean = S[t] * CDINV;
    float var = S[8 + t] * CDINV - mean * mean;
    r[t] = rsqrtf(var + 1e-5f);
  }
}

// ---- kernel 5: in-place row softmax of r*s over d=8192; one WG per (b,c) row
__global__ __launch_bounds__(256) void k_softmax(u16* __restrict__ sc,
                                                 const float* __restrict__ rb) {
  const int wg = blockIdx.x;
  const int b = wg >> 10, c = wg & 1023;
  u16* rowp = sc + (size_t)b * 8388608u + (size_t)c * 8192u;
  const float rl = rb[b] * 1.44269504089f;  // r * log2(e)
  const int t = threadIdx.x, w = t >> 6, l = t & 63;
  __shared__ float red[4];
  __shared__ float bcast;
  float v[4][8];
  float m = -1e30f;
#pragma unroll
  for (int i = 0; i < 4; ++i) {
    short8 x = *(const short8*)(rowp + i * 2048 + t * 8);
#pragma unroll
    for (int j = 0; j < 8; ++j) {
      v[i][j] = b2f((u16)x[j]);
      m = fmaxf(m, v[i][j]);
    }
  }
#pragma unroll
  for (int off = 32; off; off >>= 1) m = fmaxf(m, __shfl_xor(m, off));
  if (l == 0) red[w] = m;
  __syncthreads();
  if (t == 0) bcast = fmaxf(fmaxf(red[0], red[1]), fmaxf(red[2], red[3]));
  __syncthreads();
  m = bcast;
  float s = 0.f;
#pragma unroll
  for (int i = 0; i < 4; ++i)
#pragma unroll
    for (int j = 0; j < 8; ++j) {
      v[i][j] = exp2f((v[i][j] - m) * rl);
      s += v[i][j];
    }
#pragma unroll
  for (int off = 32; off; off >>= 1) s += __shfl_xor(s, off);
  __syncthreads();
  if (l == 0) red[w] = s;
  __syncthreads();
  if (t == 0) bcast = 1.0f / (red[0] + red[1] + red[2] + red[3]);
  __syncthreads();
  const float inv = bcast;
#pragma unroll
  for (int i = 0; i < 4; ++i) {
    short8 x;
#pragma unroll
    for (int j = 0; j < 8; ++j) x[j] = (short)f2b(v[i][j] * inv);
    *(short8*)(rowp + i * 2048 + t * 8) = x;
  }
}

// ---- kernel 6: PV = 1024x8192x8192 BT-GEMM: C'[n][(b,c)]; 128x256 tile -----
// A = v_flat row n over d (chunked: vb + (k>>10)*1M + n*1024 + (k&1023)).
// B = attn row (b*1024+c) over d, ldb=8192 (= sc). 8 waves; per-wave 64x64.
// LDS 48KB: buf p at p*24KB; A [0,8K) byte=row*64, B [8K,24K). 2-phase dbuf.
__global__ __launch_bounds__(512, 2) void k_pv2(const u16* __restrict__ vb,
                                                const u16* __restrict__ sc,
                                                u16* __restrict__ ctx) {
  __shared__ u16 lds[24576];  // 48 KiB
  char* ldsb = (char*)lds;
  const int bid = blockIdx.x;
  // XCD swizzle: xcd (bid&7) owns nt in {4x..4x+3} -> attn panels read once.
  const int nt = ((bid & 7) << 2) | (bid >> 6);
  const int mt = (bid >> 3) & 7;
  const int t = threadIdx.x, w = t >> 6, l = t & 63;
  const int wm = w >> 2, wn = w & 3;
  const int fr = l & 15, fq = l >> 4;
  const int sr0 = w * 16 + (l >> 2);
  const int kk = (l & 3) << 3;
  const int lbase = w * 1024;
  const u16* Abase = vb + (size_t)(mt * 128 + sr0) * 1024u + kk;
  const u16* B0 = sc + (size_t)(nt * 256 + sr0) * 8192u + kk;
  const int ard = (wm * 64 + fr) * 64 + fq * 16;
  const int brd = 8192 + (wn * 64 + fr) * 64 + fq * 16;

  f32x4 acc[4][4];
#pragma unroll
  for (int m = 0; m < 4; ++m)
#pragma unroll
    for (int n = 0; n < 4; ++n) acc[m][n] = (f32x4){0.f, 0.f, 0.f, 0.f};

#define PV_STAGE(s_, p_)                                                     \
  {                                                                          \
    const int k0_ = (s_) << 5;                                               \
    gll16(Abase + (size_t)(k0_ >> 10) * 1048576u + (k0_ & 1023),             \
          ldsb + (p_) * 24576 + lbase);                                      \
    char* lb_ = ldsb + (p_) * 24576 + 8192 + lbase;                          \
    gll16(B0 + k0_, lb_);                                                    \
    gll16(B0 + k0_ + 1048576, lb_ + 8192);                                   \
  }

  PV_STAGE(0, 0);
  __syncthreads();
  for (int s = 0; s < 256; ++s) {
    const int p = s & 1;
    if (s < 255) PV_STAGE(s + 1, p ^ 1);
    char* base = ldsb + p * 24576;
    bf16x8 af[4], bfv[4];
#pragma unroll
    for (int m = 0; m < 4; ++m)
      af[m] = __builtin_bit_cast(bf16x8, *(const short8*)(base + ard + m * 1024));
#pragma unroll
    for (int n = 0; n < 4; ++n)
      bfv[n] = __builtin_bit_cast(bf16x8, *(const short8*)(base + brd + n * 1024));
#pragma unroll
    for (int m = 0; m < 4; ++m)
#pragma unroll
      for (int n = 0; n < 4; ++n)
        acc[m][n] = __builtin_amdgcn_mfma_f32_16x16x32_bf16(af[m], bfv[n],
                                                            acc[m][n], 0, 0, 0);
    __syncthreads();
  }
#undef PV_STAGE

  // epilogue: ctx[b][n][c], b = nt>>2 uniform per block
  const int b = nt >> 2;
  u16* dstb = ctx + (size_t)b * 1048576u;
  const int nrow0 = mt * 128 + wm * 64 + fq * 4;
  const int c0 = ((nt & 3) << 8) + wn * 64 + fr;
#pragma unroll
  for (int m = 0; m < 4; ++m)
#pragma unroll
    for (int n = 0; n < 4; ++n) {
      const int nrow = nrow0 + m * 16;
      const int c = c0 + n * 16;
#pragma unroll
      for (int j = 0; j < 4; ++j)
        dstb[(size_t)(nrow + j) * 1024u + (size_t)c] = f2b(acc[m][n][j]);
    }
}

// ---- kernel 7: out[row][co] = sum_ch ctx[row][ch]*Wo[co][ch], f32 out ------
__global__ __launch_bounds__(256) void k_out(const u16* __restrict__ ctx,
                                             const u16* __restrict__ woB,
                                             float* __restrict__ out) {
  __shared__ u16 ldsA[4096], ldsB[4096];
  const int x = blockIdx.x;  // 64 row-tiles of 128
  f32x4 acc[4][4];
#pragma unroll
  for (int m = 0; m < 4; ++m)
#pragma unroll
    for (int n = 0; n < 4; ++n) acc[m][n] = (f32x4){0.f, 0.f, 0.f, 0.f};
  gemm_core(ctx + (size_t)x * 128u * 1024u, 1024, woB, 1024, 32, ldsA, ldsB, acc);
  const int t = threadIdx.x, w = t >> 6, l = t & 63;
  const int wr = (w >> 1) << 6, wc = (w & 1) << 6;
#pragma unroll
  for (int m = 0; m < 4; ++m)
#pragma unroll
    for (int n = 0; n < 4; ++n) {
      int rl = wr + m * 16 + ((l >> 4) << 2);
      int cl = wc + n * 16 + (l & 15);
      if (cl < 128) {
#pragma unroll
        for (int j = 0; j < 4; ++j)
          out[(size_t)(x * 128 + rl + j) * 128u + (size_t)cl] = acc[m][n][j];
      }
    }
}

extern "C" void kernel_launch(void* const* d_in, const int* in_sizes, int n_in,
                              void* d_out, int out_size, void* d_ws, size_t ws_size,
                              hipStream_t stream) {
  const float* emb = (const float*)d_in[0];
  const float* wq = (const float*)d_in[1];
  const float* wk = (const float*)d_in[2];
  const float* wv = (const float*)d_in[3];
  const float* wo = (const float*)d_in[4];
  float* out = (float*)d_out;

  char* w = (char*)d_ws;
  u16* sc = (u16*)w;                        // 8*1024*8192*2B = 134217728
  u16* qT = (u16*)(w + 134217728);          // 16 MB (aliased as ctx after QK)
  u16* kT = qT + 8388608;                   // 16 MB
  u16* vb = kT + 8388608;                   // 16 MB
  u16* embB = vb + 8388608;                 // 4 MB
  u16* wqB = embB + 2097152;
  u16* wkB = wqB + 131072;
  u16* wvB = wkB + 131072;
  u16* woB = wvB + 131072;
  float* S = (float*)(woB + 131072);        // S[0..7]=sum, S[8..15]=sumsq
  float* r = S + 16;
  u16* ctx = qT;                            // alias: qT dead after k_qk2

  k_convert<<<10240, 256, 0, stream>>>(emb, wq, wk, wv, wo, embB, wqB, wkB, wvB,
                                       woB, S);
  k_proj<<<dim3(64, 8, 3), 256, 0, stream>>>(embB, wqB, wkB, wvB, qT, kT, vb);
  k_qk2<<<1024, 512, 0, stream>>>(qT, kT, sc, S);
  k_stats<<<1, 64, 0, stream>>>(S, r);
  k_softmax<<<8192, 256, 0, stream>>>(sc, r);
  k_pv2<<<256, 512, 0, stream>>>(vb, sc, ctx);
  k_out<<<64, 256, 0, stream>>>(ctx, woB, out);
}

// Round 8
// 598.446 us; speedup vs baseline: 1.4458x; 1.0464x over previous
//
#include <hip/hip_runtime.h>
#include <stdint.h>

typedef unsigned short u16;
typedef __attribute__((ext_vector_type(8))) short short8;
typedef __attribute__((ext_vector_type(8))) __bf16 bf16x8;
typedef __attribute__((ext_vector_type(4))) float f32x4;
typedef __attribute__((ext_vector_type(4))) u16 u16x4;

// Problem constants: B2=16, N=1024, C=128, H=8, CH=1024, B=8, D=B*CH=8192
#define CDINV (1.0f / 8388608.0f)

__device__ __forceinline__ u16 f2b(float f) {
  union { float f; unsigned u; } v; v.f = f;
  unsigned r = (v.u + 0x7FFFu + ((v.u >> 16) & 1u)) >> 16;
  return (u16)r;
}
__device__ __forceinline__ float b2f(u16 h) {
  union { unsigned u; float f; } v; v.u = ((unsigned)h) << 16;
  return v.f;
}

// LDS dest is wave-uniform; hardware scatters lane i at dest + i*16.
__device__ __forceinline__ void gll16(const void* g, void* l) {
  __builtin_amdgcn_global_load_lds((const __attribute__((address_space(1))) void*)g,
                                   (__attribute__((address_space(3))) void*)l, 16, 0, 0);
}

// ---------------- m97-style core (small GEMMs: proj/out) -------------------
__device__ __forceinline__ void gemm_core(const u16* __restrict__ Ab, int lda,
                                          const u16* __restrict__ Bb, int ldb,
                                          int ksteps,
                                          u16 (&ldsA)[4096], u16 (&ldsB)[4096],
                                          f32x4 acc[4][4]) {
  const int t = threadIdx.x;
  const int w = t >> 6, l = t & 63;
  const int wr = (w >> 1) << 6, wc = (w & 1) << 6;
  const int srow = (w << 4) + (l >> 2);
  const int skk = (l & 3) << 3;
  const int fr = l & 15;
  const int fk = (l >> 4) << 3;
  for (int ks = 0; ks < ksteps; ++ks) {
    const int k0 = ks << 5;
    __syncthreads();
#pragma unroll
    for (int i = 0; i < 2; ++i) {
      gll16(Ab + (size_t)(i * 64 + srow) * (size_t)lda + (size_t)k0 + skk,
            ldsA + i * 2048 + w * 512);
      gll16(Bb + (size_t)(i * 64 + srow) * (size_t)ldb + (size_t)k0 + skk,
            ldsB + i * 2048 + w * 512);
    }
    __syncthreads();
    bf16x8 af[4], bfv[4];
#pragma unroll
    for (int m = 0; m < 4; ++m)
      af[m] = __builtin_bit_cast(bf16x8,
              *(const short8*)(ldsA + (wr + m * 16 + fr) * 32 + fk));
#pragma unroll
    for (int n = 0; n < 4; ++n)
      bfv[n] = __builtin_bit_cast(bf16x8,
              *(const short8*)(ldsB + (wc + n * 16 + fr) * 32 + fk));
#pragma unroll
    for (int m = 0; m < 4; ++m)
#pragma unroll
      for (int n = 0; n < 4; ++n)
        acc[m][n] = __builtin_amdgcn_mfma_f32_16x16x32_bf16(af[m], bfv[n],
                                                            acc[m][n], 0, 0, 0);
  }
}

// ---- kernel 1: f32 -> bf16 conversion of emb + all weights; zero stats ----
__global__ __launch_bounds__(256) void k_convert(
    const float* __restrict__ emb, const float* __restrict__ wq,
    const float* __restrict__ wk, const float* __restrict__ wv,
    const float* __restrict__ wo, u16* __restrict__ embB, u16* __restrict__ wqB,
    u16* __restrict__ wkB, u16* __restrict__ wvB, u16* __restrict__ woB,
    float* __restrict__ S) {
  int i = blockIdx.x * 256 + threadIdx.x;
  if (i < 16) S[i] = 0.0f;
  if (i < 2097152) { embB[i] = f2b(emb[i]); return; }
  int j = i - 2097152;
  if (j < 131072) { wqB[j] = f2b(wq[j]); return; }
  j -= 131072;
  if (j < 131072) { wkB[j] = f2b(wk[j]); return; }
  j -= 131072;
  if (j < 131072) { wvB[j] = f2b(wv[j]); return; }
  j -= 131072;
  if (j < 131072) { woB[j] = f2b(wo[j]); return; }
}

// ---- kernel 2: projections. q->qT[b][ch][n], k->kT[b][ch][n], v natural ----
__global__ __launch_bounds__(256) void k_proj(
    const u16* __restrict__ embB, const u16* __restrict__ wqB,
    const u16* __restrict__ wkB, const u16* __restrict__ wvB,
    u16* __restrict__ qT, u16* __restrict__ kT, u16* __restrict__ vb) {
  __shared__ u16 ldsA[4096], ldsB[4096];
  const int x = blockIdx.x, b = blockIdx.y, mat = blockIdx.z;
  const int n0 = (x & 7) << 7, ch0 = (x >> 3) << 7;
  const int rowbase = ((mat == 0 ? b : b + 8) << 10) + n0;
  const u16* W = (mat == 0) ? wqB : ((mat == 1) ? wkB : wvB);
  f32x4 acc[4][4];
#pragma unroll
  for (int m = 0; m < 4; ++m)
#pragma unroll
    for (int n = 0; n < 4; ++n) acc[m][n] = (f32x4){0.f, 0.f, 0.f, 0.f};
  gemm_core(embB + (size_t)rowbase * 128, 128, W + (size_t)ch0 * 128, 128, 4,
            ldsA, ldsB, acc);
  const int t = threadIdx.x, w = t >> 6, l = t & 63;
  const int wr = (w >> 1) << 6, wc = (w & 1) << 6;
  if (mat < 2) {
    u16* dst = (mat == 0 ? qT : kT) + (size_t)b * 1048576u;
#pragma unroll
    for (int m = 0; m < 4; ++m)
#pragma unroll
      for (int n = 0; n < 4; ++n) {
        int rl = wr + m * 16 + ((l >> 4) << 2);
        int cl = wc + n * 16 + (l & 15);
        u16x4 pk;
#pragma unroll
        for (int j = 0; j < 4; ++j) pk[j] = f2b(acc[m][n][j]);
        *(u16x4*)(dst + (size_t)(ch0 + cl) * 1024u + (size_t)(n0 + rl)) = pk;
      }
  } else {
    u16* dst = vb + (size_t)b * 1048576u;
#pragma unroll
    for (int m = 0; m < 4; ++m)
#pragma unroll
      for (int n = 0; n < 4; ++n) {
        int rl = wr + m * 16 + ((l >> 4) << 2);
        int cl = wc + n * 16 + (l & 15);
#pragma unroll
        for (int j = 0; j < 4; ++j)
          dst[(size_t)(n0 + rl + j) * 1024u + (size_t)(ch0 + cl)] = f2b(acc[m][n][j]);
      }
  }
}

// Swizzle scheme (both-sides, rule #21): LDS 16B-chunk (row, s') holds global
// k-slot s' ^ ((row>>2)&3). Stage source permutes chunks within each 64B row
// (coalescing preserved); reads pick slot fq ^ (fr>>2) -> 2-way banks (free).

__device__ __forceinline__ void qk_compute(char* base, int ard, int brd,
                                           f32x4 (&acc)[8][4]) {
  bf16x8 af[8], bfv[4];
#pragma unroll
  for (int m = 0; m < 8; ++m)
    af[m] = __builtin_bit_cast(bf16x8, *(const short8*)(base + ard + m * 1024));
#pragma unroll
  for (int n = 0; n < 4; ++n)
    bfv[n] = __builtin_bit_cast(bf16x8, *(const short8*)(base + brd + n * 1024));
#pragma unroll
  for (int m = 0; m < 8; ++m)
#pragma unroll
    for (int n = 0; n < 4; ++n)
      acc[m][n] = __builtin_amdgcn_mfma_f32_16x16x32_bf16(af[m], bfv[n],
                                                          acc[m][n], 0, 0, 0);
}

// ---- kernel 3: QK = 8192x8192x1024 BT-GEMM, 256x256 tile, counted-vmcnt ---
// Per step: barrier1 (WAR: all read prev buf) -> STAGE(next) -> vmcnt(4)
// (own stage-s landed) -> barrier2 (all stage-s visible) -> ds_read+MFMA.
// Prefetch stays in flight across the MFMA phase (no full drain).
__global__ __launch_bounds__(512, 2) void k_qk2(const u16* __restrict__ qT,
                                                const u16* __restrict__ kT,
                                                u16* __restrict__ sc,
                                                float* __restrict__ S) {
  __shared__ u16 lds[32768];  // 64 KiB (<= 64KB workgroup limit!)
  char* ldsb = (char*)lds;
  const int bid = blockIdx.x;
  const int mt = (bid & 7) * 4 + (bid >> 8);  // XCD swizzle
  const int nt = (bid >> 3) & 31;
  const int t = threadIdx.x, w = t >> 6, l = t & 63;
  const int wm = w >> 2, wn = w & 3;
  const int fr = l & 15, fq = l >> 4;
  const int sr0 = w * 16 + (l >> 2);                    // staged row
  const int kk = (((l & 3) ^ ((l >> 4) & 3)) << 3);     // swizzled src k-chunk
  const int lbase = w * 1024;                           // wave-uniform LDS base
  const u16* A0 = qT + (size_t)(mt * 256 + sr0) * 1024u + kk;
  const u16* B0 = kT + (size_t)(nt * 256 + sr0) * 1024u + kk;
  const int swz = ((fq ^ (fr >> 2)) << 4);              // swizzled read slot
  const int ard = (wm * 128 + fr) * 64 + swz;
  const int brd = 16384 + (wn * 64 + fr) * 64 + swz;

  f32x4 acc[8][4];
#pragma unroll
  for (int m = 0; m < 8; ++m)
#pragma unroll
    for (int n = 0; n < 4; ++n) acc[m][n] = (f32x4){0.f, 0.f, 0.f, 0.f};

#define QK_STAGE(s_, p_)                                                    \
  {                                                                         \
    const int k0_ = (s_) << 5;                                              \
    char* la_ = ldsb + (p_) * 32768 + lbase;                                \
    gll16(A0 + k0_, la_);                                                   \
    gll16(A0 + k0_ + 131072, la_ + 8192);                                   \
    char* lb_ = ldsb + (p_) * 32768 + 16384 + lbase;                        \
    gll16(B0 + k0_, lb_);                                                   \
    gll16(B0 + k0_ + 131072, lb_ + 8192);                                   \
  }

  QK_STAGE(0, 0);
  for (int s = 0; s < 31; ++s) {
    const int p = s & 1;
    __builtin_amdgcn_s_barrier();            // all waves done reading buf p^1
    __builtin_amdgcn_sched_barrier(0);
    QK_STAGE(s + 1, p ^ 1);
    asm volatile("s_waitcnt vmcnt(4)" ::: "memory");  // stage-s landed (own)
    __builtin_amdgcn_sched_barrier(0);
    __builtin_amdgcn_s_barrier();            // everyone's stage-s visible
    __builtin_amdgcn_sched_barrier(0);
    asm volatile("" ::: "memory");
    qk_compute(ldsb + p * 32768, ard, brd, acc);
  }
  __builtin_amdgcn_s_barrier();
  __builtin_amdgcn_sched_barrier(0);
  asm volatile("s_waitcnt vmcnt(0)" ::: "memory");
  __builtin_amdgcn_sched_barrier(0);
  __builtin_amdgcn_s_barrier();
  __builtin_amdgcn_sched_barrier(0);
  asm volatile("" ::: "memory");
  qk_compute(ldsb + 32768, ard, brd, acc);   // step 31, p = 1
#undef QK_STAGE

  // epilogue: bf16 stores + per-batch sum/sumsq atomics
  const int mrow0 = mt * 256 + wm * 128 + fq * 4;
  const int ncol0 = nt * 256 + wn * 64 + fr;
  const int b = mt >> 2;  // uniform per block
  float ls = 0.f, lq = 0.f;
#pragma unroll
  for (int m = 0; m < 8; ++m)
#pragma unroll
    for (int n = 0; n < 4; ++n) {
      const int row = mrow0 + m * 16;
      const int col = ncol0 + n * 16;
#pragma unroll
      for (int j = 0; j < 4; ++j) {
        float sv = acc[m][n][j];
        ls += sv; lq += sv * sv;
        sc[(size_t)(row + j) * 8192u + (size_t)col] = f2b(sv);
      }
    }
#pragma unroll
  for (int off = 32; off; off >>= 1) {
    ls += __shfl_down(ls, off);
    lq += __shfl_down(lq, off);
  }
  if (l == 0) { atomicAdd(&S[b], ls); atomicAdd(&S[8 + b], lq); }
}

// ---- kernel 4: per-batch rsqrt(var+eps). mean shift cancels in softmax. ----
__global__ void k_stats(const float* __restrict__ S, float* __restrict__ r) {
  int t = threadIdx.x;
  if (t < 8) {
    float mean = S[t] * CDINV;
    float var = S[8 + t] * CDINV - mean * mean;
    r[t] = rsqrtf(var + 1e-5f);
  }
}

// ---- kernel 5: in-place row softmax of r*s over d=8192; one WG per (b,c) row
__global__ __launch_bounds__(256) void k_softmax(u16* __restrict__ sc,
                                                 const float* __restrict__ rb) {
  const int wg = blockIdx.x;
  const int b = wg >> 10, c = wg & 1023;
  u16* rowp = sc + (size_t)b * 8388608u + (size_t)c * 8192u;
  const float rl = rb[b] * 1.44269504089f;  // r * log2(e)
  const int t = threadIdx.x, w = t >> 6, l = t & 63;
  __shared__ float red[4];
  __shared__ float bcast;
  float v[4][8];
  float m = -1e30f;
#pragma unroll
  for (int i = 0; i < 4; ++i) {
    short8 x = *(const short8*)(rowp + i * 2048 + t * 8);
#pragma unroll
    for (int j = 0; j < 8; ++j) {
      v[i][j] = b2f((u16)x[j]);
      m = fmaxf(m, v[i][j]);
    }
  }
#pragma unroll
  for (int off = 32; off; off >>= 1) m = fmaxf(m, __shfl_xor(m, off));
  if (l == 0) red[w] = m;
  __syncthreads();
  if (t == 0) bcast = fmaxf(fmaxf(red[0], red[1]), fmaxf(red[2], red[3]));
  __syncthreads();
  m = bcast;
  float s = 0.f;
#pragma unroll
  for (int i = 0; i < 4; ++i)
#pragma unroll
    for (int j = 0; j < 8; ++j) {
      v[i][j] = exp2f((v[i][j] - m) * rl);
      s += v[i][j];
    }
#pragma unroll
  for (int off = 32; off; off >>= 1) s += __shfl_xor(s, off);
  __syncthreads();
  if (l == 0) red[w] = s;
  __syncthreads();
  if (t == 0) bcast = 1.0f / (red[0] + red[1] + red[2] + red[3]);
  __syncthreads();
  const float inv = bcast;
#pragma unroll
  for (int i = 0; i < 4; ++i) {
    short8 x;
#pragma unroll
    for (int j = 0; j < 8; ++j) x[j] = (short)f2b(v[i][j] * inv);
    *(short8*)(rowp + i * 2048 + t * 8) = x;
  }
}

__device__ __forceinline__ void pv_compute(char* base, int ard, int brd,
                                           f32x4 (&acc)[4][4]) {
  bf16x8 af[4], bfv[4];
#pragma unroll
  for (int m = 0; m < 4; ++m)
    af[m] = __builtin_bit_cast(bf16x8, *(const short8*)(base + ard + m * 1024));
#pragma unroll
  for (int n = 0; n < 4; ++n)
    bfv[n] = __builtin_bit_cast(bf16x8, *(const short8*)(base + brd + n * 1024));
#pragma unroll
  for (int m = 0; m < 4; ++m)
#pragma unroll
    for (int n = 0; n < 4; ++n)
      acc[m][n] = __builtin_amdgcn_mfma_f32_16x16x32_bf16(af[m], bfv[n],
                                                          acc[m][n], 0, 0, 0);
}

// ---- kernel 6: PV = 1024x8192x8192 BT-GEMM: C'[n][(b,c)]; 128x256 tile -----
// Counted-vmcnt schedule as in k_qk2 (3 loads/stage -> vmcnt(3)).
__global__ __launch_bounds__(512, 2) void k_pv2(const u16* __restrict__ vb,
                                                const u16* __restrict__ sc,
                                                u16* __restrict__ ctx) {
  __shared__ u16 lds[24576];  // 48 KiB
  char* ldsb = (char*)lds;
  const int bid = blockIdx.x;
  const int nt = ((bid & 7) << 2) | (bid >> 6);  // XCD owns 4 nt panels
  const int mt = (bid >> 3) & 7;
  const int t = threadIdx.x, w = t >> 6, l = t & 63;
  const int wm = w >> 2, wn = w & 3;
  const int fr = l & 15, fq = l >> 4;
  const int sr0 = w * 16 + (l >> 2);
  const int kk = (((l & 3) ^ ((l >> 4) & 3)) << 3);     // swizzled src k-chunk
  const int lbase = w * 1024;
  const u16* Abase = vb + (size_t)(mt * 128 + sr0) * 1024u + kk;
  const u16* B0 = sc + (size_t)(nt * 256 + sr0) * 8192u + kk;
  const int swz = ((fq ^ (fr >> 2)) << 4);
  const int ard = (wm * 64 + fr) * 64 + swz;
  const int brd = 8192 + (wn * 64 + fr) * 64 + swz;

  f32x4 acc[4][4];
#pragma unroll
  for (int m = 0; m < 4; ++m)
#pragma unroll
    for (int n = 0; n < 4; ++n) acc[m][n] = (f32x4){0.f, 0.f, 0.f, 0.f};

#define PV_STAGE(s_, p_)                                                     \
  {                                                                          \
    const int k0_ = (s_) << 5;                                               \
    gll16(Abase + (size_t)(k0_ >> 10) * 1048576u + (k0_ & 1023),             \
          ldsb + (p_) * 24576 + lbase);                                      \
    char* lb_ = ldsb + (p_) * 24576 + 8192 + lbase;                          \
    gll16(B0 + k0_, lb_);                                                    \
    gll16(B0 + k0_ + 1048576, lb_ + 8192);                                   \
  }

  PV_STAGE(0, 0);
  for (int s = 0; s < 255; ++s) {
    const int p = s & 1;
    __builtin_amdgcn_s_barrier();
    __builtin_amdgcn_sched_barrier(0);
    PV_STAGE(s + 1, p ^ 1);
    asm volatile("s_waitcnt vmcnt(3)" ::: "memory");
    __builtin_amdgcn_sched_barrier(0);
    __builtin_amdgcn_s_barrier();
    __builtin_amdgcn_sched_barrier(0);
    asm volatile("" ::: "memory");
    pv_compute(ldsb + p * 24576, ard, brd, acc);
  }
  __builtin_amdgcn_s_barrier();
  __builtin_amdgcn_sched_barrier(0);
  asm volatile("s_waitcnt vmcnt(0)" ::: "memory");
  __builtin_amdgcn_sched_barrier(0);
  __builtin_amdgcn_s_barrier();
  __builtin_amdgcn_sched_barrier(0);
  asm volatile("" ::: "memory");
  pv_compute(ldsb + 24576, ard, brd, acc);   // step 255, p = 1
#undef PV_STAGE

  // epilogue: ctx[b][n][c], b = nt>>2 uniform per block
  const int b = nt >> 2;
  u16* dstb = ctx + (size_t)b * 1048576u;
  const int nrow0 = mt * 128 + wm * 64 + fq * 4;
  const int c0 = ((nt & 3) << 8) + wn * 64 + fr;
#pragma unroll
  for (int m = 0; m < 4; ++m)
#pragma unroll
    for (int n = 0; n < 4; ++n) {
      const int nrow = nrow0 + m * 16;
      const int c = c0 + n * 16;
#pragma unroll
      for (int j = 0; j < 4; ++j)
        dstb[(size_t)(nrow + j) * 1024u + (size_t)c] = f2b(acc[m][n][j]);
    }
}

// ---- kernel 7: out[row][co] = sum_ch ctx[row][ch]*Wo[co][ch], f32 out ------
__global__ __launch_bounds__(256) void k_out(const u16* __restrict__ ctx,
                                             const u16* __restrict__ woB,
                                             float* __restrict__ out) {
  __shared__ u16 ldsA[4096], ldsB[4096];
  const int x = blockIdx.x;  // 64 row-tiles of 128
  f32x4 acc[4][4];
#pragma unroll
  for (int m = 0; m < 4; ++m)
#pragma unroll
    for (int n = 0; n < 4; ++n) acc[m][n] = (f32x4){0.f, 0.f, 0.f, 0.f};
  gemm_core(ctx + (size_t)x * 128u * 1024u, 1024, woB, 1024, 32, ldsA, ldsB, acc);
  const int t = threadIdx.x, w = t >> 6, l = t & 63;
  const int wr = (w >> 1) << 6, wc = (w & 1) << 6;
#pragma unroll
  for (int m = 0; m < 4; ++m)
#pragma unroll
    for (int n = 0; n < 4; ++n) {
      int rl = wr + m * 16 + ((l >> 4) << 2);
      int cl = wc + n * 16 + (l & 15);
      if (cl < 128) {
#pragma unroll
        for (int j = 0; j < 4; ++j)
          out[(size_t)(x * 128 + rl + j) * 128u + (size_t)cl] = acc[m][n][j];
      }
    }
}

extern "C" void kernel_launch(void* const* d_in, const int* in_sizes, int n_in,
                              void* d_out, int out_size, void* d_ws, size_t ws_size,
                              hipStream_t stream) {
  const float* emb = (const float*)d_in[0];
  const float* wq = (const float*)d_in[1];
  const float* wk = (const float*)d_in[2];
  const float* wv = (const float*)d_in[3];
  const float* wo = (const float*)d_in[4];
  float* out = (float*)d_out;

  char* w = (char*)d_ws;
  u16* sc = (u16*)w;                        // 8*1024*8192*2B = 134217728
  u16* qT = (u16*)(w + 134217728);          // 16 MB (aliased as ctx after QK)
  u16* kT = qT + 8388608;                   // 16 MB
  u16* vb = kT + 8388608;                   // 16 MB
  u16* embB = vb + 8388608;                 // 4 MB
  u16* wqB = embB + 2097152;
  u16* wkB = wqB + 131072;
  u16* wvB = wkB + 131072;
  u16* woB = wvB + 131072;
  float* S = (float*)(woB + 131072);        // S[0..7]=sum, S[8..15]=sumsq
  float* r = S + 16;
  u16* ctx = qT;                            // alias: qT dead after k_qk2

  k_convert<<<10240, 256, 0, stream>>>(emb, wq, wk, wv, wo, embB, wqB, wkB, wvB,
                                       woB, S);
  k_proj<<<dim3(64, 8, 3), 256, 0, stream>>>(embB, wqB, wkB, wvB, qT, kT, vb);
  k_qk2<<<1024, 512, 0, stream>>>(qT, kT, sc, S);
  k_stats<<<1, 64, 0, stream>>>(S, r);
  k_softmax<<<8192, 256, 0, stream>>>(sc, r);
  k_pv2<<<256, 512, 0, stream>>>(vb, sc, ctx);
  k_out<<<64, 256, 0, stream>>>(ctx, woB, out);
}

// Round 9
// 580.794 us; speedup vs baseline: 1.4898x; 1.0304x over previous
//
#include <hip/hip_runtime.h>
#include <stdint.h>

typedef unsigned short u16;
typedef __attribute__((ext_vector_type(8))) short short8;
typedef __attribute__((ext_vector_type(8))) __bf16 bf16x8;
typedef __attribute__((ext_vector_type(4))) float f32x4;
typedef __attribute__((ext_vector_type(4))) u16 u16x4;

// Problem constants: B2=16, N=1024, C=128, H=8, CH=1024, B=8, D=B*CH=8192
#define CDINV (1.0f / 8388608.0f)

__device__ __forceinline__ u16 f2b(float f) {
  union { float f; unsigned u; } v; v.f = f;
  unsigned r = (v.u + 0x7FFFu + ((v.u >> 16) & 1u)) >> 16;
  return (u16)r;
}
__device__ __forceinline__ float b2f(u16 h) {
  union { unsigned u; float f; } v; v.u = ((unsigned)h) << 16;
  return v.f;
}

// LDS dest is wave-uniform; hardware scatters lane i at dest + i*16.
__device__ __forceinline__ void gll16(const void* g, void* l) {
  __builtin_amdgcn_global_load_lds((const __attribute__((address_space(1))) void*)g,
                                   (__attribute__((address_space(3))) void*)l, 16, 0, 0);
}

// ---------------- m97-style core (small GEMMs: proj/out) -------------------
__device__ __forceinline__ void gemm_core(const u16* __restrict__ Ab, int lda,
                                          const u16* __restrict__ Bb, int ldb,
                                          int ksteps,
                                          u16 (&ldsA)[4096], u16 (&ldsB)[4096],
                                          f32x4 acc[4][4]) {
  const int t = threadIdx.x;
  const int w = t >> 6, l = t & 63;
  const int wr = (w >> 1) << 6, wc = (w & 1) << 6;
  const int srow = (w << 4) + (l >> 2);
  const int skk = (l & 3) << 3;
  const int fr = l & 15;
  const int fk = (l >> 4) << 3;
  for (int ks = 0; ks < ksteps; ++ks) {
    const int k0 = ks << 5;
    __syncthreads();
#pragma unroll
    for (int i = 0; i < 2; ++i) {
      gll16(Ab + (size_t)(i * 64 + srow) * (size_t)lda + (size_t)k0 + skk,
            ldsA + i * 2048 + w * 512);
      gll16(Bb + (size_t)(i * 64 + srow) * (size_t)ldb + (size_t)k0 + skk,
            ldsB + i * 2048 + w * 512);
    }
    __syncthreads();
    bf16x8 af[4], bfv[4];
#pragma unroll
    for (int m = 0; m < 4; ++m)
      af[m] = __builtin_bit_cast(bf16x8,
              *(const short8*)(ldsA + (wr + m * 16 + fr) * 32 + fk));
#pragma unroll
    for (int n = 0; n < 4; ++n)
      bfv[n] = __builtin_bit_cast(bf16x8,
              *(const short8*)(ldsB + (wc + n * 16 + fr) * 32 + fk));
#pragma unroll
    for (int m = 0; m < 4; ++m)
#pragma unroll
      for (int n = 0; n < 4; ++n)
        acc[m][n] = __builtin_amdgcn_mfma_f32_16x16x32_bf16(af[m], bfv[n],
                                                            acc[m][n], 0, 0, 0);
  }
}

// ---- kernel 1: f32 -> bf16 conversion of emb + all weights; zero stats ----
__global__ __launch_bounds__(256) void k_convert(
    const float* __restrict__ emb, const float* __restrict__ wq,
    const float* __restrict__ wk, const float* __restrict__ wv,
    const float* __restrict__ wo, u16* __restrict__ embB, u16* __restrict__ wqB,
    u16* __restrict__ wkB, u16* __restrict__ wvB, u16* __restrict__ woB,
    float* __restrict__ S) {
  int i = blockIdx.x * 256 + threadIdx.x;
  if (i < 16) S[i] = 0.0f;
  if (i < 2097152) { embB[i] = f2b(emb[i]); return; }
  int j = i - 2097152;
  if (j < 131072) { wqB[j] = f2b(wq[j]); return; }
  j -= 131072;
  if (j < 131072) { wkB[j] = f2b(wk[j]); return; }
  j -= 131072;
  if (j < 131072) { wvB[j] = f2b(wv[j]); return; }
  j -= 131072;
  if (j < 131072) { woB[j] = f2b(wo[j]); return; }
}

// ---- kernel 2: projections. q->qT[b][ch][n], k->kT[b][ch][n], v natural ----
__global__ __launch_bounds__(256) void k_proj(
    const u16* __restrict__ embB, const u16* __restrict__ wqB,
    const u16* __restrict__ wkB, const u16* __restrict__ wvB,
    u16* __restrict__ qT, u16* __restrict__ kT, u16* __restrict__ vb) {
  __shared__ u16 ldsA[4096], ldsB[4096];
  const int x = blockIdx.x, b = blockIdx.y, mat = blockIdx.z;
  const int n0 = (x & 7) << 7, ch0 = (x >> 3) << 7;
  const int rowbase = ((mat == 0 ? b : b + 8) << 10) + n0;
  const u16* W = (mat == 0) ? wqB : ((mat == 1) ? wkB : wvB);
  f32x4 acc[4][4];
#pragma unroll
  for (int m = 0; m < 4; ++m)
#pragma unroll
    for (int n = 0; n < 4; ++n) acc[m][n] = (f32x4){0.f, 0.f, 0.f, 0.f};
  gemm_core(embB + (size_t)rowbase * 128, 128, W + (size_t)ch0 * 128, 128, 4,
            ldsA, ldsB, acc);
  const int t = threadIdx.x, w = t >> 6, l = t & 63;
  const int wr = (w >> 1) << 6, wc = (w & 1) << 6;
  if (mat < 2) {
    u16* dst = (mat == 0 ? qT : kT) + (size_t)b * 1048576u;
#pragma unroll
    for (int m = 0; m < 4; ++m)
#pragma unroll
      for (int n = 0; n < 4; ++n) {
        int rl = wr + m * 16 + ((l >> 4) << 2);
        int cl = wc + n * 16 + (l & 15);
        u16x4 pk;
#pragma unroll
        for (int j = 0; j < 4; ++j) pk[j] = f2b(acc[m][n][j]);
        *(u16x4*)(dst + (size_t)(ch0 + cl) * 1024u + (size_t)(n0 + rl)) = pk;
      }
  } else {
    u16* dst = vb + (size_t)b * 1048576u;
#pragma unroll
    for (int m = 0; m < 4; ++m)
#pragma unroll
      for (int n = 0; n < 4; ++n) {
        int rl = wr + m * 16 + ((l >> 4) << 2);
        int cl = wc + n * 16 + (l & 15);
#pragma unroll
        for (int j = 0; j < 4; ++j)
          dst[(size_t)(n0 + rl + j) * 1024u + (size_t)(ch0 + cl)] = f2b(acc[m][n][j]);
      }
  }
}

// ---- kernel 3: QK = 8192x8192x1024 BT-GEMM, 256x256 tile, 2-phase dbuf ----
// Round-5 proven schedule: STAGE(next) -> compute(cur) -> __syncthreads.
__global__ __launch_bounds__(512, 2) void k_qk2(const u16* __restrict__ qT,
                                                const u16* __restrict__ kT,
                                                u16* __restrict__ sc,
                                                float* __restrict__ S) {
  __shared__ u16 lds[32768];  // 64 KiB (runtime per-WG limit!)
  char* ldsb = (char*)lds;
  const int bid = blockIdx.x;
  const int mt = (bid & 7) * 4 + (bid >> 8);  // XCD swizzle
  const int nt = (bid >> 3) & 31;
  const int t = threadIdx.x, w = t >> 6, l = t & 63;
  const int wm = w >> 2, wn = w & 3;
  const int fr = l & 15, fq = l >> 4;
  const int sr0 = w * 16 + (l >> 2);   // staged row; 4 lanes per row
  const int kk = (l & 3) << 3;         // k-chunk within sub-tile (elements)
  const int lbase = w * 1024;          // wave-uniform LDS byte base
  const u16* A0 = qT + (size_t)(mt * 256 + sr0) * 1024u + kk;
  const u16* B0 = kT + (size_t)(nt * 256 + sr0) * 1024u + kk;
  const int ard = (wm * 128 + fr) * 64 + fq * 16;
  const int brd = 16384 + (wn * 64 + fr) * 64 + fq * 16;

  f32x4 acc[8][4];
#pragma unroll
  for (int m = 0; m < 8; ++m)
#pragma unroll
    for (int n = 0; n < 4; ++n) acc[m][n] = (f32x4){0.f, 0.f, 0.f, 0.f};

#define QK_STAGE(s_, p_)                                                    \
  {                                                                         \
    const int k0_ = (s_) << 5;                                              \
    char* la_ = ldsb + (p_) * 32768 + lbase;                                \
    gll16(A0 + k0_, la_);                                                   \
    gll16(A0 + k0_ + 131072, la_ + 8192);                                   \
    char* lb_ = ldsb + (p_) * 32768 + 16384 + lbase;                        \
    gll16(B0 + k0_, lb_);                                                   \
    gll16(B0 + k0_ + 131072, lb_ + 8192);                                   \
  }

  QK_STAGE(0, 0);
  __syncthreads();
  for (int s = 0; s < 32; ++s) {
    const int p = s & 1;
    if (s < 31) QK_STAGE(s + 1, p ^ 1);  // issue next tile before compute
    char* base = ldsb + p * 32768;
    bf16x8 af[8], bfv[4];
#pragma unroll
    for (int m = 0; m < 8; ++m)
      af[m] = __builtin_bit_cast(bf16x8, *(const short8*)(base + ard + m * 1024));
#pragma unroll
    for (int n = 0; n < 4; ++n)
      bfv[n] = __builtin_bit_cast(bf16x8, *(const short8*)(base + brd + n * 1024));
#pragma unroll
    for (int m = 0; m < 8; ++m)
#pragma unroll
      for (int n = 0; n < 4; ++n)
        acc[m][n] = __builtin_amdgcn_mfma_f32_16x16x32_bf16(af[m], bfv[n],
                                                            acc[m][n], 0, 0, 0);
    __syncthreads();  // drains vmcnt(0): next buffer complete; WAR protected
  }
#undef QK_STAGE

  // epilogue: bf16 stores + per-batch sum/sumsq atomics
  const int mrow0 = mt * 256 + wm * 128 + fq * 4;
  const int ncol0 = nt * 256 + wn * 64 + fr;
  const int b = mt >> 2;  // uniform per block
  float ls = 0.f, lq = 0.f;
#pragma unroll
  for (int m = 0; m < 8; ++m)
#pragma unroll
    for (int n = 0; n < 4; ++n) {
      const int row = mrow0 + m * 16;
      const int col = ncol0 + n * 16;
#pragma unroll
      for (int j = 0; j < 4; ++j) {
        float sv = acc[m][n][j];
        ls += sv; lq += sv * sv;
        sc[(size_t)(row + j) * 8192u + (size_t)col] = f2b(sv);
      }
    }
#pragma unroll
  for (int off = 32; off; off >>= 1) {
    ls += __shfl_down(ls, off);
    lq += __shfl_down(lq, off);
  }
  if (l == 0) { atomicAdd(&S[b], ls); atomicAdd(&S[8 + b], lq); }
}

// ---- kernel 4: in-place row softmax of r*s over d=8192; one WG per row ----
// Per-batch rsqrt(var+eps) computed inline from S (stats kernel folded in);
// mean shift cancels in softmax.
__global__ __launch_bounds__(256) void k_softmax(u16* __restrict__ sc,
                                                 const float* __restrict__ S) {
  const int wg = blockIdx.x;
  const int b = wg >> 10, c = wg & 1023;
  u16* rowp = sc + (size_t)b * 8388608u + (size_t)c * 8192u;
  const float mean = S[b] * CDINV;
  const float var = S[8 + b] * CDINV - mean * mean;
  const float rl = rsqrtf(var + 1e-5f) * 1.44269504089f;  // r * log2(e)
  const int t = threadIdx.x, w = t >> 6, l = t & 63;
  __shared__ float red[4];
  __shared__ float bcast;
  float v[4][8];
  float m = -1e30f;
#pragma unroll
  for (int i = 0; i < 4; ++i) {
    short8 x = *(const short8*)(rowp + i * 2048 + t * 8);
#pragma unroll
    for (int j = 0; j < 8; ++j) {
      v[i][j] = b2f((u16)x[j]);
      m = fmaxf(m, v[i][j]);
    }
  }
#pragma unroll
  for (int off = 32; off; off >>= 1) m = fmaxf(m, __shfl_xor(m, off));
  if (l == 0) red[w] = m;
  __syncthreads();
  if (t == 0) bcast = fmaxf(fmaxf(red[0], red[1]), fmaxf(red[2], red[3]));
  __syncthreads();
  m = bcast;
  float s = 0.f;
#pragma unroll
  for (int i = 0; i < 4; ++i)
#pragma unroll
    for (int j = 0; j < 8; ++j) {
      v[i][j] = exp2f((v[i][j] - m) * rl);
      s += v[i][j];
    }
#pragma unroll
  for (int off = 32; off; off >>= 1) s += __shfl_xor(s, off);
  __syncthreads();
  if (l == 0) red[w] = s;
  __syncthreads();
  if (t == 0) bcast = 1.0f / (red[0] + red[1] + red[2] + red[3]);
  __syncthreads();
  const float inv = bcast;
#pragma unroll
  for (int i = 0; i < 4; ++i) {
    short8 x;
#pragma unroll
    for (int j = 0; j < 8; ++j) x[j] = (short)f2b(v[i][j] * inv);
    *(short8*)(rowp + i * 2048 + t * 8) = x;
  }
}

__device__ __forceinline__ void pv_compute(char* base, int ard, int brd,
                                           f32x4 (&acc)[4][4]) {
  bf16x8 af[4], bfv[4];
#pragma unroll
  for (int m = 0; m < 4; ++m)
    af[m] = __builtin_bit_cast(bf16x8, *(const short8*)(base + ard + m * 1024));
#pragma unroll
  for (int n = 0; n < 4; ++n)
    bfv[n] = __builtin_bit_cast(bf16x8, *(const short8*)(base + brd + n * 1024));
#pragma unroll
  for (int m = 0; m < 4; ++m)
#pragma unroll
    for (int n = 0; n < 4; ++n)
      acc[m][n] = __builtin_amdgcn_mfma_f32_16x16x32_bf16(af[m], bfv[n],
                                                          acc[m][n], 0, 0, 0);
}

// ---- kernel 5: PV = 1024x8192x8192 BT-GEMM: C'[n][(b,c)]; 128x256 tile -----
// Round-8 proven counted-vmcnt schedule (PV is overhead/latency-exposed:
// counted-vmcnt helped here even though it was neutral-negative on QK).
__global__ __launch_bounds__(512, 2) void k_pv2(const u16* __restrict__ vb,
                                                const u16* __restrict__ sc,
                                                u16* __restrict__ ctx) {
  __shared__ u16 lds[24576];  // 48 KiB
  char* ldsb = (char*)lds;
  const int bid = blockIdx.x;
  const int nt = ((bid & 7) << 2) | (bid >> 6);  // XCD owns 4 nt panels
  const int mt = (bid >> 3) & 7;
  const int t = threadIdx.x, w = t >> 6, l = t & 63;
  const int wm = w >> 2, wn = w & 3;
  const int fr = l & 15, fq = l >> 4;
  const int sr0 = w * 16 + (l >> 2);
  const int kk = (((l & 3) ^ ((l >> 4) & 3)) << 3);     // swizzled src k-chunk
  const int lbase = w * 1024;
  const u16* Abase = vb + (size_t)(mt * 128 + sr0) * 1024u + kk;
  const u16* B0 = sc + (size_t)(nt * 256 + sr0) * 8192u + kk;
  const int swz = ((fq ^ (fr >> 2)) << 4);
  const int ard = (wm * 64 + fr) * 64 + swz;
  const int brd = 8192 + (wn * 64 + fr) * 64 + swz;

  f32x4 acc[4][4];
#pragma unroll
  for (int m = 0; m < 4; ++m)
#pragma unroll
    for (int n = 0; n < 4; ++n) acc[m][n] = (f32x4){0.f, 0.f, 0.f, 0.f};

#define PV_STAGE(s_, p_)                                                     \
  {                                                                          \
    const int k0_ = (s_) << 5;                                               \
    gll16(Abase + (size_t)(k0_ >> 10) * 1048576u + (k0_ & 1023),             \
          ldsb + (p_) * 24576 + lbase);                                      \
    char* lb_ = ldsb + (p_) * 24576 + 8192 + lbase;                          \
    gll16(B0 + k0_, lb_);                                                    \
    gll16(B0 + k0_ + 1048576, lb_ + 8192);                                   \
  }

  PV_STAGE(0, 0);
  for (int s = 0; s < 255; ++s) {
    const int p = s & 1;
    __builtin_amdgcn_s_barrier();
    __builtin_amdgcn_sched_barrier(0);
    PV_STAGE(s + 1, p ^ 1);
    asm volatile("s_waitcnt vmcnt(3)" ::: "memory");
    __builtin_amdgcn_sched_barrier(0);
    __builtin_amdgcn_s_barrier();
    __builtin_amdgcn_sched_barrier(0);
    asm volatile("" ::: "memory");
    pv_compute(ldsb + p * 24576, ard, brd, acc);
  }
  __builtin_amdgcn_s_barrier();
  __builtin_amdgcn_sched_barrier(0);
  asm volatile("s_waitcnt vmcnt(0)" ::: "memory");
  __builtin_amdgcn_sched_barrier(0);
  __builtin_amdgcn_s_barrier();
  __builtin_amdgcn_sched_barrier(0);
  asm volatile("" ::: "memory");
  pv_compute(ldsb + 24576, ard, brd, acc);   // step 255, p = 1
#undef PV_STAGE

  // epilogue: ctx[b][n][c], b = nt>>2 uniform per block
  const int b = nt >> 2;
  u16* dstb = ctx + (size_t)b * 1048576u;
  const int nrow0 = mt * 128 + wm * 64 + fq * 4;
  const int c0 = ((nt & 3) << 8) + wn * 64 + fr;
#pragma unroll
  for (int m = 0; m < 4; ++m)
#pragma unroll
    for (int n = 0; n < 4; ++n) {
      const int nrow = nrow0 + m * 16;
      const int c = c0 + n * 16;
#pragma unroll
      for (int j = 0; j < 4; ++j)
        dstb[(size_t)(nrow + j) * 1024u + (size_t)c] = f2b(acc[m][n][j]);
    }
}

// ---- kernel 6: out[row][co] = sum_ch ctx[row][ch]*Wo[co][ch], f32 out ------
__global__ __launch_bounds__(256) void k_out(const u16* __restrict__ ctx,
                                             const u16* __restrict__ woB,
                                             float* __restrict__ out) {
  __shared__ u16 ldsA[4096], ldsB[4096];
  const int x = blockIdx.x;  // 64 row-tiles of 128
  f32x4 acc[4][4];
#pragma unroll
  for (int m = 0; m < 4; ++m)
#pragma unroll
    for (int n = 0; n < 4; ++n) acc[m][n] = (f32x4){0.f, 0.f, 0.f, 0.f};
  gemm_core(ctx + (size_t)x * 128u * 1024u, 1024, woB, 1024, 32, ldsA, ldsB, acc);
  const int t = threadIdx.x, w = t >> 6, l = t & 63;
  const int wr = (w >> 1) << 6, wc = (w & 1) << 6;
#pragma unroll
  for (int m = 0; m < 4; ++m)
#pragma unroll
    for (int n = 0; n < 4; ++n) {
      int rl = wr + m * 16 + ((l >> 4) << 2);
      int cl = wc + n * 16 + (l & 15);
      if (cl < 128) {
#pragma unroll
        for (int j = 0; j < 4; ++j)
          out[(size_t)(x * 128 + rl + j) * 128u + (size_t)cl] = acc[m][n][j];
      }
    }
}

extern "C" void kernel_launch(void* const* d_in, const int* in_sizes, int n_in,
                              void* d_out, int out_size, void* d_ws, size_t ws_size,
                              hipStream_t stream) {
  const float* emb = (const float*)d_in[0];
  const float* wq = (const float*)d_in[1];
  const float* wk = (const float*)d_in[2];
  const float* wv = (const float*)d_in[3];
  const float* wo = (const float*)d_in[4];
  float* out = (float*)d_out;

  char* w = (char*)d_ws;
  u16* sc = (u16*)w;                        // 8*1024*8192*2B = 134217728
  u16* qT = (u16*)(w + 134217728);          // 16 MB (aliased as ctx after QK)
  u16* kT = qT + 8388608;                   // 16 MB
  u16* vb = kT + 8388608;                   // 16 MB
  u16* embB = vb + 8388608;                 // 4 MB
  u16* wqB = embB + 2097152;
  u16* wkB = wqB + 131072;
  u16* wvB = wkB + 131072;
  u16* woB = wvB + 131072;
  float* S = (float*)(woB + 131072);        // S[0..7]=sum, S[8..15]=sumsq
  u16* ctx = qT;                            // alias: qT dead after k_qk2

  k_convert<<<10240, 256, 0, stream>>>(emb, wq, wk, wv, wo, embB, wqB, wkB, wvB,
                                       woB, S);
  k_proj<<<dim3(64, 8, 3), 256, 0, stream>>>(embB, wqB, wkB, wvB, qT, kT, vb);
  k_qk2<<<1024, 512, 0, stream>>>(qT, kT, sc, S);
  k_softmax<<<8192, 256, 0, stream>>>(sc, S);
  k_pv2<<<256, 512, 0, stream>>>(vb, sc, ctx);
  k_out<<<64, 256, 0, stream>>>(ctx, woB, out);
}